// Round 7
// baseline (96.597 us; speedup 1.0000x reference)
//
#include <hip/hip_runtime.h>
#include <math.h>

#define N_NODE 10
#define N_FEAT 8
#define HID 80
#define IN_DIM 40

typedef __attribute__((ext_vector_type(8))) short bf16x8;
typedef __attribute__((ext_vector_type(4))) float f32x4;
typedef __attribute__((ext_vector_type(4))) unsigned uint4v;

#define NFRAG 19          // 10 layer-1 + 9 layer-2 fragments, 1KB each

// Manual RNE fp32->bf16 (pack kernels only; finite inputs).
__device__ __forceinline__ short f2bf(float f) {
    unsigned u = __builtin_bit_cast(unsigned, f);
    u += 0x7fffu + ((u >> 16) & 1u);
    return (short)(u >> 16);
}

// HW packed convert: lo->bits[15:0], hi->bits[31:16], RNE. Register-only asm.
__device__ __forceinline__ unsigned cvtpk(float lo, float hi) {
    unsigned r;
    asm("v_cvt_pk_bf16_f32 %0, %1, %2" : "=v"(r) : "v"(lo), "v"(hi));
    return r;
}

// ws layout (floats): [0,3200) W_mid | [3200,3240) b_mid | [3240,...) frags
#define FRAG_OFF 3240

// ---------------------------------------------------------------------------
// Fold GraphConv (fixed circulant adjacency) + W_rel/W_root + decoder into
// W_mid [HID][IN_DIM], b_mid [IN_DIM]:  out = relu(relu(x@W_enc+b_enc)@W_mid+b_mid)
// ---------------------------------------------------------------------------
__global__ void precompute_kernel(const float* __restrict__ W_rel,
                                  const float* __restrict__ b_rel,
                                  const float* __restrict__ W_root,
                                  const float* __restrict__ W_dec,
                                  const float* __restrict__ b_dec,
                                  float* __restrict__ W_mid,
                                  float* __restrict__ b_mid)
{
    const float w = expf(-1.0f / 9.0f);
    const int idx = blockIdx.x * blockDim.x + threadIdx.x;
    const int nthr = gridDim.x * blockDim.x;

    for (int e = idx; e < HID * IN_DIM; e += nthr) {
        const int o  = e % IN_DIM;
        const int sf = e / IN_DIM;
        const int s  = sf / N_FEAT;
        const int f  = sf % N_FEAT;
        const int sp = (s + 1) % N_NODE;
        const int sm = (s + N_NODE - 1) % N_NODE;
        float acc = 0.0f;
        #pragma unroll
        for (int g = 0; g < N_FEAT; ++g) {
            acc = fmaf(W_root[f * N_FEAT + g], W_dec[(s  * N_FEAT + g) * IN_DIM + o], acc);
            acc = fmaf(w * W_rel[f * N_FEAT + g],
                       W_dec[(sp * N_FEAT + g) * IN_DIM + o] +
                       W_dec[(sm * N_FEAT + g) * IN_DIM + o], acc);
        }
        W_mid[e] = acc;
    }

    for (int o = idx; o < IN_DIM; o += nthr) {
        float acc = b_dec[o];
        #pragma unroll
        for (int t = 0; t < N_NODE; ++t)
            #pragma unroll
            for (int g = 0; g < N_FEAT; ++g)
                acc = fmaf(b_rel[g], W_dec[(t * N_FEAT + g) * IN_DIM + o], acc);
        b_mid[o] = acc;
    }
}

// ---------------------------------------------------------------------------
// Pack bf16 weight fragments (biases riding spare k-slots) into ws.
//   Wf1[t][s] lane(m,q) elem e : k=32s+8q+e              -> W_enc[k][16t+m], k==40 -> b_enc
//   Wf2[t][s] lane(m,q) elem e : n=32s+16(e>>2)+4q+(e&3) -> W_mid[n][16t+m], n==80 -> b_mid
// ---------------------------------------------------------------------------
__global__ void pack_frags_kernel(const float* __restrict__ W_enc,
                                  const float* __restrict__ b_enc,
                                  float* __restrict__ ws)
{
    const int lane = threadIdx.x;           // 64 threads
    const int m = lane & 15;
    const int q = lane >> 4;
    const float* W_mid = ws;
    const float* b_mid = ws + HID * IN_DIM;
    unsigned* fb = (unsigned*)(ws + FRAG_OFF);

    #pragma unroll
    for (int t = 0; t < 5; ++t)
        #pragma unroll
        for (int s = 0; s < 2; ++s) {
            short v[8];
            #pragma unroll
            for (int e = 0; e < 8; ++e) {
                const int k = 32 * s + 8 * q + e;
                float f = 0.0f;
                if (k < IN_DIM)       f = W_enc[k * HID + 16 * t + m];
                else if (k == IN_DIM) f = b_enc[16 * t + m];
                v[e] = f2bf(f);
            }
            const int fid = t * 2 + s;
            #pragma unroll
            for (int j = 0; j < 4; ++j)
                fb[fid * 256 + lane * 4 + j] =
                    (unsigned)(unsigned short)v[2 * j] |
                    ((unsigned)(unsigned short)v[2 * j + 1] << 16);
        }

    #pragma unroll
    for (int t = 0; t < 3; ++t) {
        const int o = 16 * t + m;
        #pragma unroll
        for (int s = 0; s < 3; ++s) {
            short v[8];
            #pragma unroll
            for (int e = 0; e < 8; ++e) {
                const int n = 32 * s + 16 * (e >> 2) + 4 * q + (e & 3);
                float f = 0.0f;
                if (o < IN_DIM) {
                    if (n < HID)       f = W_mid[n * IN_DIM + o];
                    else if (n == HID) f = b_mid[o];
                }
                v[e] = f2bf(f);
            }
            const int fid = 10 + t * 3 + s;
            #pragma unroll
            for (int j = 0; j < 4; ++j)
                fb[fid * 256 + lane * 4 + j] =
                    (unsigned)(unsigned short)v[2 * j] |
                    ((unsigned)(unsigned short)v[2 * j + 1] << 16);
        }
    }
}

// ---------------------------------------------------------------------------
// Fused MLP: weights in LDS (low VGPR), forced 8 waves/SIMD, persistent grid,
// and 1-deep x prefetch so each iteration's loads are issued BEFORE the
// previous iteration's stores in program order. vmcnt retires in issue order,
// so the dependent wait for the loads leaves the (younger) stores in flight —
// store-to-HBM drain never sits on the critical path.
// Layer 1 (A=Wf1, B=x^T): lane(m,q) gets y[m][16t+4q+r].
// Layer 2 (A=Wf2, B=P, k-map n=32s+16(e>>2)+4q+(e&3)): lane gets
// out[m][16t+4q+r] -> 3 per-lane float4 stores. Biases ride spare k-slots.
// ---------------------------------------------------------------------------
__global__ __launch_bounds__(256, 8) void fused_mfma_kernel(
    const float* __restrict__ x,
    const float* __restrict__ ws,
    float* __restrict__ out,
    int B, int ntiles)
{
    __shared__ uint4v wlds[NFRAG * 64];     // 19 KiB

    const int tid  = threadIdx.x;
    const int wave = tid >> 6;
    const int lane = tid & 63;
    const int m = lane & 15;
    const int q = lane >> 4;

    // ---- block prologue: stage all weight fragments into LDS ----
    {
        const uint4v* fb = (const uint4v*)(ws + FRAG_OFF);
        #pragma unroll
        for (int i = tid; i < NFRAG * 64; i += 256)
            wlds[i] = fb[i];
    }
    __syncthreads();

    const int nw = gridDim.x * 4;           // total waves
    const uint4v* wl = wlds + lane;         // frag f at wl[f*64]

    int it = blockIdx.x * 4 + wave;
    if (it >= ntiles) return;

#define LOADX(P0_, P1_, P2_, P3_, IT)                                          \
    {                                                                          \
        P0_.x=0.f;P0_.y=0.f;P0_.z=0.f;P0_.w=0.f; P1_=P0_; P2_=P0_; P3_=P0_;    \
        if ((IT) < ntiles) {                                                   \
            const int row_ = (IT) * 16 + m;                                    \
            if (row_ < B) {                                                    \
                const float* xr_ = x + (size_t)row_ * IN_DIM;                  \
                P0_ = *(const float4*)(xr_ + 8 * q);                           \
                P1_ = *(const float4*)(xr_ + 8 * q + 4);                       \
                if (q == 0) {                                                  \
                    P2_ = *(const float4*)(xr_ + 32);                          \
                    P3_ = *(const float4*)(xr_ + 36);                          \
                }                                                              \
            }                                                                  \
        }                                                                      \
    }

    float4 c0, c1, c2, c3;     // current tile
    float4 d0, d1, d2, d3;     // prefetched next tile
    LOADX(c0, c1, c2, c3, it);

    while (true) {
        const int itn = it + nw;

        // ---- prefetch next tile: issued BEFORE this tile's stores ----
        LOADX(d0, d1, d2, d3, itn);

        // ---- x fragments via packed converts (lane holds x[m][32s+8q+e]) ----
        uint4v xu0, xu1;
        xu0.x = cvtpk(c0.x, c0.y); xu0.y = cvtpk(c0.z, c0.w);
        xu0.z = cvtpk(c1.x, c1.y); xu0.w = cvtpk(c1.z, c1.w);
        xu1.x = (q == 1) ? 0x3F80u : cvtpk(c2.x, c2.y);   // 1.0 at bias k-slot 40
        xu1.y = cvtpk(c2.z, c2.w);
        xu1.z = cvtpk(c3.x, c3.y); xu1.w = cvtpk(c3.z, c3.w);
        const bf16x8 X0 = __builtin_bit_cast(bf16x8, xu0);
        const bf16x8 X1 = __builtin_bit_cast(bf16x8, xu1);

        // ---- layer 1: JIT LDS weight reads, lane gets y[m][16t+4q+r] ----
        f32x4 acc1[5];
        #pragma unroll
        for (int t = 0; t < 5; ++t) { acc1[t][0]=0.f; acc1[t][1]=0.f; acc1[t][2]=0.f; acc1[t][3]=0.f; }
        #pragma unroll
        for (int t = 0; t < 5; ++t) {
            const bf16x8 w0 = __builtin_bit_cast(bf16x8, wl[(t * 2 + 0) * 64]);
            acc1[t] = __builtin_amdgcn_mfma_f32_16x16x32_bf16(w0, X0, acc1[t], 0, 0, 0);
            const bf16x8 w1 = __builtin_bit_cast(bf16x8, wl[(t * 2 + 1) * 64]);
            acc1[t] = __builtin_amdgcn_mfma_f32_16x16x32_bf16(w1, X1, acc1[t], 0, 0, 0);
        }

        // ---- relu + packed repack: layer-2 B-fragment IS acc1 under k-map ----
        float r0, r1;
        uint4v pu0, pu1, pu2;
        r0 = fmaxf(acc1[0][0], 0.f); r1 = fmaxf(acc1[0][1], 0.f); pu0.x = cvtpk(r0, r1);
        r0 = fmaxf(acc1[0][2], 0.f); r1 = fmaxf(acc1[0][3], 0.f); pu0.y = cvtpk(r0, r1);
        r0 = fmaxf(acc1[1][0], 0.f); r1 = fmaxf(acc1[1][1], 0.f); pu0.z = cvtpk(r0, r1);
        r0 = fmaxf(acc1[1][2], 0.f); r1 = fmaxf(acc1[1][3], 0.f); pu0.w = cvtpk(r0, r1);
        r0 = fmaxf(acc1[2][0], 0.f); r1 = fmaxf(acc1[2][1], 0.f); pu1.x = cvtpk(r0, r1);
        r0 = fmaxf(acc1[2][2], 0.f); r1 = fmaxf(acc1[2][3], 0.f); pu1.y = cvtpk(r0, r1);
        r0 = fmaxf(acc1[3][0], 0.f); r1 = fmaxf(acc1[3][1], 0.f); pu1.z = cvtpk(r0, r1);
        r0 = fmaxf(acc1[3][2], 0.f); r1 = fmaxf(acc1[3][3], 0.f); pu1.w = cvtpk(r0, r1);
        r0 = fmaxf(acc1[4][0], 0.f); r1 = fmaxf(acc1[4][1], 0.f); pu2.x = cvtpk(r0, r1);
        r0 = fmaxf(acc1[4][2], 0.f); r1 = fmaxf(acc1[4][3], 0.f); pu2.y = cvtpk(r0, r1);
        pu2.z = (q == 0) ? 0x3F80u : 0u;       // 1.0 at bias n-slot 80
        pu2.w = 0u;
        const bf16x8 P0 = __builtin_bit_cast(bf16x8, pu0);
        const bf16x8 P1 = __builtin_bit_cast(bf16x8, pu1);
        const bf16x8 P2 = __builtin_bit_cast(bf16x8, pu2);

        // ---- layer 2: JIT LDS weight reads, lane gets out[m][16t+4q+r] ----
        f32x4 acc2[3];
        #pragma unroll
        for (int t = 0; t < 3; ++t) { acc2[t][0]=0.f; acc2[t][1]=0.f; acc2[t][2]=0.f; acc2[t][3]=0.f; }
        #pragma unroll
        for (int t = 0; t < 3; ++t) {
            const bf16x8 w0 = __builtin_bit_cast(bf16x8, wl[(10 + t * 3 + 0) * 64]);
            acc2[t] = __builtin_amdgcn_mfma_f32_16x16x32_bf16(w0, P0, acc2[t], 0, 0, 0);
            const bf16x8 w1 = __builtin_bit_cast(bf16x8, wl[(10 + t * 3 + 1) * 64]);
            acc2[t] = __builtin_amdgcn_mfma_f32_16x16x32_bf16(w1, P1, acc2[t], 0, 0, 0);
            const bf16x8 w2 = __builtin_bit_cast(bf16x8, wl[(10 + t * 3 + 2) * 64]);
            acc2[t] = __builtin_amdgcn_mfma_f32_16x16x32_bf16(w2, P2, acc2[t], 0, 0, 0);
        }

        // ---- relu + per-lane float4 stores (younger than next tile's loads) ----
        {
            const int row = it * 16 + m;
            if (row < B) {
                float* orow = out + (size_t)row * IN_DIM;
                #pragma unroll
                for (int t = 0; t < 3; ++t) {
                    const int o0 = 16 * t + 4 * q;
                    if (o0 < IN_DIM) {
                        float4 v;
                        v.x = fmaxf(acc2[t][0], 0.f);
                        v.y = fmaxf(acc2[t][1], 0.f);
                        v.z = fmaxf(acc2[t][2], 0.f);
                        v.w = fmaxf(acc2[t][3], 0.f);
                        *(float4*)(orow + o0) = v;
                    }
                }
            }
        }

        if (itn >= ntiles) break;
        c0 = d0; c1 = d1; c2 = d2; c3 = d3;
        it = itn;
    }
#undef LOADX
}

extern "C" void kernel_launch(void* const* d_in, const int* in_sizes, int n_in,
                              void* d_out, int out_size, void* d_ws, size_t ws_size,
                              hipStream_t stream)
{
    const float* x      = (const float*)d_in[0];
    const float* W_enc  = (const float*)d_in[1];
    const float* b_enc  = (const float*)d_in[2];
    const float* W_rel  = (const float*)d_in[3];
    const float* b_rel  = (const float*)d_in[4];
    const float* W_root = (const float*)d_in[5];
    const float* W_dec  = (const float*)d_in[6];
    const float* b_dec  = (const float*)d_in[7];
    float* out = (float*)d_out;

    const int B = in_sizes[0] / IN_DIM;
    const int ntiles = (B + 15) / 16;

    float* ws = (float*)d_ws;
    float* W_mid = ws;                       // [0, 3200)
    float* b_mid = ws + HID * IN_DIM;        // [3200, 3240)

    precompute_kernel<<<13, 256, 0, stream>>>(W_rel, b_rel, W_root, W_dec, b_dec,
                                              W_mid, b_mid);
    pack_frags_kernel<<<1, 64, 0, stream>>>(W_enc, b_enc, ws);

    // Persistent grid: 2048 blocks = 8 blocks/CU (LDS-capped), all co-resident.
    const int grid = 2048;
    fused_mfma_kernel<<<grid, 256, 0, stream>>>(x, ws, out, B, ntiles);
}

// Round 8
// 83.928 us; speedup vs baseline: 1.1510x; 1.1510x over previous
//
#include <hip/hip_runtime.h>
#include <math.h>

#define N_NODE 10
#define N_FEAT 8
#define HID 80
#define IN_DIM 40

typedef __attribute__((ext_vector_type(8))) short bf16x8;
typedef __attribute__((ext_vector_type(4))) float f32x4;
typedef __attribute__((ext_vector_type(4))) unsigned uint4v;

#define NFRAG 19          // 10 layer-1 + 9 layer-2 fragments, 1KB each
#define ROWB  176         // padded LDS row stride (44 words: 16B-aligned, bank-balanced)
#define STRIPB (16 * ROWB)
#define TILEB 2560        // 16 rows x 160B, contiguous in x / out

// Manual RNE fp32->bf16 (pack kernels only; finite inputs).
__device__ __forceinline__ short f2bf(float f) {
    unsigned u = __builtin_bit_cast(unsigned, f);
    u += 0x7fffu + ((u >> 16) & 1u);
    return (short)(u >> 16);
}

// HW packed convert: lo->bits[15:0], hi->bits[31:16], RNE. Register-only asm.
__device__ __forceinline__ unsigned cvtpk(float lo, float hi) {
    unsigned r;
    asm("v_cvt_pk_bf16_f32 %0, %1, %2" : "=v"(r) : "v"(lo), "v"(hi));
    return r;
}

// ws layout (floats): [0,3200) W_mid | [3200,3240) b_mid | [3240,...) frags
#define FRAG_OFF 3240

// ---------------------------------------------------------------------------
// Fold GraphConv (fixed circulant adjacency) + W_rel/W_root + decoder into
// W_mid [HID][IN_DIM], b_mid [IN_DIM]:  out = relu(relu(x@W_enc+b_enc)@W_mid+b_mid)
// ---------------------------------------------------------------------------
__global__ void precompute_kernel(const float* __restrict__ W_rel,
                                  const float* __restrict__ b_rel,
                                  const float* __restrict__ W_root,
                                  const float* __restrict__ W_dec,
                                  const float* __restrict__ b_dec,
                                  float* __restrict__ W_mid,
                                  float* __restrict__ b_mid)
{
    const float w = expf(-1.0f / 9.0f);
    const int idx = blockIdx.x * blockDim.x + threadIdx.x;
    const int nthr = gridDim.x * blockDim.x;

    for (int e = idx; e < HID * IN_DIM; e += nthr) {
        const int o  = e % IN_DIM;
        const int sf = e / IN_DIM;
        const int s  = sf / N_FEAT;
        const int f  = sf % N_FEAT;
        const int sp = (s + 1) % N_NODE;
        const int sm = (s + N_NODE - 1) % N_NODE;
        float acc = 0.0f;
        #pragma unroll
        for (int g = 0; g < N_FEAT; ++g) {
            acc = fmaf(W_root[f * N_FEAT + g], W_dec[(s  * N_FEAT + g) * IN_DIM + o], acc);
            acc = fmaf(w * W_rel[f * N_FEAT + g],
                       W_dec[(sp * N_FEAT + g) * IN_DIM + o] +
                       W_dec[(sm * N_FEAT + g) * IN_DIM + o], acc);
        }
        W_mid[e] = acc;
    }

    for (int o = idx; o < IN_DIM; o += nthr) {
        float acc = b_dec[o];
        #pragma unroll
        for (int t = 0; t < N_NODE; ++t)
            #pragma unroll
            for (int g = 0; g < N_FEAT; ++g)
                acc = fmaf(b_rel[g], W_dec[(t * N_FEAT + g) * IN_DIM + o], acc);
        b_mid[o] = acc;
    }
}

// ---------------------------------------------------------------------------
// Pack bf16 weight fragments (biases riding spare k-slots) into ws.
//   Wf1[t][s] lane(m,q) elem e : k=32s+8q+e              -> W_enc[k][16t+m], k==40 -> b_enc
//   Wf2[t][s] lane(m,q) elem e : n=32s+16(e>>2)+4q+(e&3) -> W_mid[n][16t+m], n==80 -> b_mid
// ---------------------------------------------------------------------------
__global__ void pack_frags_kernel(const float* __restrict__ W_enc,
                                  const float* __restrict__ b_enc,
                                  float* __restrict__ ws)
{
    const int lane = threadIdx.x;           // 64 threads
    const int m = lane & 15;
    const int q = lane >> 4;
    const float* W_mid = ws;
    const float* b_mid = ws + HID * IN_DIM;
    unsigned* fb = (unsigned*)(ws + FRAG_OFF);

    #pragma unroll
    for (int t = 0; t < 5; ++t)
        #pragma unroll
        for (int s = 0; s < 2; ++s) {
            short v[8];
            #pragma unroll
            for (int e = 0; e < 8; ++e) {
                const int k = 32 * s + 8 * q + e;
                float f = 0.0f;
                if (k < IN_DIM)       f = W_enc[k * HID + 16 * t + m];
                else if (k == IN_DIM) f = b_enc[16 * t + m];
                v[e] = f2bf(f);
            }
            const int fid = t * 2 + s;
            #pragma unroll
            for (int j = 0; j < 4; ++j)
                fb[fid * 256 + lane * 4 + j] =
                    (unsigned)(unsigned short)v[2 * j] |
                    ((unsigned)(unsigned short)v[2 * j + 1] << 16);
        }

    #pragma unroll
    for (int t = 0; t < 3; ++t) {
        const int o = 16 * t + m;
        #pragma unroll
        for (int s = 0; s < 3; ++s) {
            short v[8];
            #pragma unroll
            for (int e = 0; e < 8; ++e) {
                const int n = 32 * s + 16 * (e >> 2) + 4 * q + (e & 3);
                float f = 0.0f;
                if (o < IN_DIM) {
                    if (n < HID)       f = W_mid[n * IN_DIM + o];
                    else if (n == HID) f = b_mid[o];
                }
                v[e] = f2bf(f);
            }
            const int fid = 10 + t * 3 + s;
            #pragma unroll
            for (int j = 0; j < 4; ++j)
                fb[fid * 256 + lane * 4 + j] =
                    (unsigned)(unsigned short)v[2 * j] |
                    ((unsigned)(unsigned short)v[2 * j + 1] << 16);
        }
    }
}

// ---------------------------------------------------------------------------
// Fused MLP with FULLY COALESCED global memory: every global load/store is a
// 64-lane x 16B contiguous (1KB) transaction. The MFMA fragment scatter
// happens in LDS via a per-wave-private padded strip (row stride 176B:
// 16B-aligned b128 ops, uniform 8 words/bank = LDS-pipe minimum).
// Per tile: A) 3 coalesced loads (next tile) -> regs; B) ds_read fragments,
// cvt, MFMA L1, repack, MFMA L2; C) acc2 -> strip (MFMA layout); D) linear
// readback + 3 coalesced stores; E) stage prefetched regs -> strip.
// Loads precede stores in program order -> waits are vmcnt(3)-class, stores
// stay in flight. Wave-private strip: no barriers; per-wave DS pipe is
// in-order so C-after-B-reads and E-after-D-reads are safe.
// ---------------------------------------------------------------------------
__global__ __launch_bounds__(256, 5) void fused_mfma_kernel(
    const float* __restrict__ x,
    const float* __restrict__ ws,
    float* __restrict__ out,
    int B, int ntiles)
{
    __shared__ uint4v wlds[NFRAG * 64];                    // 19456 B
    __shared__ __align__(16) char strip_all[4][STRIPB];    // 11264 B

    const int tid  = threadIdx.x;
    const int wave = tid >> 6;
    const int lane = tid & 63;
    const int m = lane & 15;
    const int q = lane >> 4;

    // ---- block prologue: stage all weight fragments into LDS ----
    {
        const uint4v* fb = (const uint4v*)(ws + FRAG_OFF);
        #pragma unroll
        for (int i = tid; i < NFRAG * 64; i += 256)
            wlds[i] = fb[i];
    }
    __syncthreads();

    char* sp = strip_all[wave];
    const uint4v* wl = wlds + lane;                        // frag f at wl[f*64]
    const char* xptr = (const char*)x;
    char* optr = (char*)out;
    const size_t xbytes = (size_t)B * (IN_DIM * 4);        // == out bytes

    // per-lane constants: chunk cl -> strip addr (row cl/10, col 16*(cl%10)),
    // global byte offset cl*16. 160 chunks = 2 full-wave + 1 half-wave ops.
    const int cl0 = lane,      cl1 = lane + 64, cl2 = lane + 128;
    const int sta0 = (cl0 / 10) * ROWB + (cl0 % 10) * 16;
    const int sta1 = (cl1 / 10) * ROWB + (cl1 % 10) * 16;
    const int sta2 = (cl2 / 10) * ROWB + (cl2 % 10) * 16;
    const int gb0 = cl0 * 16, gb1 = cl1 * 16, gb2 = cl2 * 16;
    const bool has2 = (lane < 32);
    const int xrow = ROWB * m;                             // fragment row base

    const int nw = gridDim.x * 4;
    int it = blockIdx.x * 4 + wave;
    if (it >= ntiles) return;

#define LDG(D_, GB_, IT_, EXTRA_)                                              \
    { D_.x = 0u; D_.y = 0u; D_.z = 0u; D_.w = 0u;                              \
      if ((EXTRA_) && (IT_) < ntiles) {                                        \
          const size_t off_ = (size_t)(IT_) * TILEB + (GB_);                   \
          if (off_ + 16 <= xbytes) D_ = *(const uint4v*)(xptr + off_);         \
      } }

    // ---- prologue: load + stage tile `it` ----
    {
        uint4v a0, a1, a2;
        LDG(a0, gb0, it, true); LDG(a1, gb1, it, true); LDG(a2, gb2, it, has2);
        *(uint4v*)(sp + sta0) = a0;
        *(uint4v*)(sp + sta1) = a1;
        if (has2) *(uint4v*)(sp + sta2) = a2;
    }

    while (true) {
        const int itn = it + nw;

        // ---- A: coalesced prefetch of next tile (oldest VMEM this iter) ----
        uint4v n0, n1, n2;
        LDG(n0, gb0, itn, true); LDG(n1, gb1, itn, true); LDG(n2, gb2, itn, has2);
        __builtin_amdgcn_sched_barrier(0);

        // ---- B: fragments from strip (bank-balanced b128 reads) ----
        const f32x4 xa = *(const f32x4*)(sp + xrow + 32 * q);
        const f32x4 xb = *(const f32x4*)(sp + xrow + 32 * q + 16);
        uint4v xu0;
        xu0.x = cvtpk(xa[0], xa[1]); xu0.y = cvtpk(xa[2], xa[3]);
        xu0.z = cvtpk(xb[0], xb[1]); xu0.w = cvtpk(xb[2], xb[3]);
        uint4v xu1;
        if (q == 0) {
            const f32x4 xc = *(const f32x4*)(sp + xrow + 128);
            const f32x4 xd = *(const f32x4*)(sp + xrow + 144);
            xu1.x = cvtpk(xc[0], xc[1]); xu1.y = cvtpk(xc[2], xc[3]);
            xu1.z = cvtpk(xd[0], xd[1]); xu1.w = cvtpk(xd[2], xd[3]);
        } else {
            xu1.x = (q == 1) ? 0x3F80u : 0u;   // 1.0 at bias k-slot 40
            xu1.y = 0u; xu1.z = 0u; xu1.w = 0u;
        }
        const bf16x8 X0 = __builtin_bit_cast(bf16x8, xu0);
        const bf16x8 X1 = __builtin_bit_cast(bf16x8, xu1);

        // layer 1 (swapped): lane gets y[m][16t+4q+r]
        f32x4 acc1[5];
        #pragma unroll
        for (int t = 0; t < 5; ++t) { acc1[t][0]=0.f; acc1[t][1]=0.f; acc1[t][2]=0.f; acc1[t][3]=0.f; }
        #pragma unroll
        for (int t = 0; t < 5; ++t) {
            const bf16x8 w0 = __builtin_bit_cast(bf16x8, wl[(t * 2 + 0) * 64]);
            acc1[t] = __builtin_amdgcn_mfma_f32_16x16x32_bf16(w0, X0, acc1[t], 0, 0, 0);
            const bf16x8 w1 = __builtin_bit_cast(bf16x8, wl[(t * 2 + 1) * 64]);
            acc1[t] = __builtin_amdgcn_mfma_f32_16x16x32_bf16(w1, X1, acc1[t], 0, 0, 0);
        }

        // relu + packed repack: layer-2 B-fragment IS acc1 under the k-map
        float r0, r1;
        uint4v pu0, pu1, pu2;
        r0 = fmaxf(acc1[0][0], 0.f); r1 = fmaxf(acc1[0][1], 0.f); pu0.x = cvtpk(r0, r1);
        r0 = fmaxf(acc1[0][2], 0.f); r1 = fmaxf(acc1[0][3], 0.f); pu0.y = cvtpk(r0, r1);
        r0 = fmaxf(acc1[1][0], 0.f); r1 = fmaxf(acc1[1][1], 0.f); pu0.z = cvtpk(r0, r1);
        r0 = fmaxf(acc1[1][2], 0.f); r1 = fmaxf(acc1[1][3], 0.f); pu0.w = cvtpk(r0, r1);
        r0 = fmaxf(acc1[2][0], 0.f); r1 = fmaxf(acc1[2][1], 0.f); pu1.x = cvtpk(r0, r1);
        r0 = fmaxf(acc1[2][2], 0.f); r1 = fmaxf(acc1[2][3], 0.f); pu1.y = cvtpk(r0, r1);
        r0 = fmaxf(acc1[3][0], 0.f); r1 = fmaxf(acc1[3][1], 0.f); pu1.z = cvtpk(r0, r1);
        r0 = fmaxf(acc1[3][2], 0.f); r1 = fmaxf(acc1[3][3], 0.f); pu1.w = cvtpk(r0, r1);
        r0 = fmaxf(acc1[4][0], 0.f); r1 = fmaxf(acc1[4][1], 0.f); pu2.x = cvtpk(r0, r1);
        r0 = fmaxf(acc1[4][2], 0.f); r1 = fmaxf(acc1[4][3], 0.f); pu2.y = cvtpk(r0, r1);
        pu2.z = (q == 0) ? 0x3F80u : 0u;       // 1.0 at bias n-slot 80
        pu2.w = 0u;
        const bf16x8 P0 = __builtin_bit_cast(bf16x8, pu0);
        const bf16x8 P1 = __builtin_bit_cast(bf16x8, pu1);
        const bf16x8 P2 = __builtin_bit_cast(bf16x8, pu2);

        // layer 2 (swapped): lane gets out[m][16t+4q+r]
        f32x4 acc2[3];
        #pragma unroll
        for (int t = 0; t < 3; ++t) { acc2[t][0]=0.f; acc2[t][1]=0.f; acc2[t][2]=0.f; acc2[t][3]=0.f; }
        #pragma unroll
        for (int t = 0; t < 3; ++t) {
            const bf16x8 w0 = __builtin_bit_cast(bf16x8, wl[(10 + t * 3 + 0) * 64]);
            acc2[t] = __builtin_amdgcn_mfma_f32_16x16x32_bf16(w0, P0, acc2[t], 0, 0, 0);
            const bf16x8 w1 = __builtin_bit_cast(bf16x8, wl[(10 + t * 3 + 1) * 64]);
            acc2[t] = __builtin_amdgcn_mfma_f32_16x16x32_bf16(w1, P1, acc2[t], 0, 0, 0);
            const bf16x8 w2 = __builtin_bit_cast(bf16x8, wl[(10 + t * 3 + 2) * 64]);
            acc2[t] = __builtin_amdgcn_mfma_f32_16x16x32_bf16(w2, P2, acc2[t], 0, 0, 0);
        }

        // ---- C: relu + scatter out-tile into strip (MFMA layout) ----
        #pragma unroll
        for (int t = 0; t < 3; ++t) {
            const int o0 = 16 * t + 4 * q;
            if (o0 < IN_DIM) {
                f32x4 v;
                v[0] = fmaxf(acc2[t][0], 0.f);
                v[1] = fmaxf(acc2[t][1], 0.f);
                v[2] = fmaxf(acc2[t][2], 0.f);
                v[3] = fmaxf(acc2[t][3], 0.f);
                *(f32x4*)(sp + xrow + 64 * t + 16 * q) = v;
            }
        }

        // ---- D: linear readback + fully coalesced global stores ----
        {
            const size_t ob = (size_t)it * TILEB;
            const uint4v s0 = *(const uint4v*)(sp + sta0);
            const uint4v s1 = *(const uint4v*)(sp + sta1);
            if (ob + gb0 + 16 <= xbytes) *(uint4v*)(optr + ob + gb0) = s0;
            if (ob + gb1 + 16 <= xbytes) *(uint4v*)(optr + ob + gb1) = s1;
            if (has2) {
                const uint4v s2 = *(const uint4v*)(sp + sta2);
                if (ob + gb2 + 16 <= xbytes) *(uint4v*)(optr + ob + gb2) = s2;
            }
        }
        __builtin_amdgcn_sched_barrier(0);

        if (itn >= ntiles) break;

        // ---- E: stage prefetched tile into strip (waits vmcnt for loads
        //        only; the younger stores from D remain in flight) ----
        *(uint4v*)(sp + sta0) = n0;
        *(uint4v*)(sp + sta1) = n1;
        if (has2) *(uint4v*)(sp + sta2) = n2;
        it = itn;
    }
#undef LDG
}

extern "C" void kernel_launch(void* const* d_in, const int* in_sizes, int n_in,
                              void* d_out, int out_size, void* d_ws, size_t ws_size,
                              hipStream_t stream)
{
    const float* x      = (const float*)d_in[0];
    const float* W_enc  = (const float*)d_in[1];
    const float* b_enc  = (const float*)d_in[2];
    const float* W_rel  = (const float*)d_in[3];
    const float* b_rel  = (const float*)d_in[4];
    const float* W_root = (const float*)d_in[5];
    const float* W_dec  = (const float*)d_in[6];
    const float* b_dec  = (const float*)d_in[7];
    float* out = (float*)d_out;

    const int B = in_sizes[0] / IN_DIM;
    const int ntiles = (B + 15) / 16;

    float* ws = (float*)d_ws;
    float* W_mid = ws;                       // [0, 3200)
    float* b_mid = ws + HID * IN_DIM;        // [3200, 3240)

    precompute_kernel<<<13, 256, 0, stream>>>(W_rel, b_rel, W_root, W_dec, b_dec,
                                              W_mid, b_mid);
    pack_frags_kernel<<<1, 64, 0, stream>>>(W_enc, b_enc, ws);

    // Persistent grid: 5 blocks/CU (30KB LDS each) x 256 CUs, all co-resident.
    const int grid = 1280;
    fused_mfma_kernel<<<grid, 256, 0, stream>>>(x, ws, out, B, ntiles);
}